// Round 15
// baseline (77.469 us; speedup 1.0000x reference)
//
#include <hip/hip_runtime.h>
#include <math.h>

typedef __attribute__((ext_vector_type(8))) short short8;
typedef __attribute__((ext_vector_type(4))) float f32x4;
typedef __attribute__((ext_vector_type(2))) float f32x2;

__device__ inline short f2bf(float f) {
    unsigned u = __float_as_uint(f);
    u += 0x7FFFu + ((u >> 16) & 1u);   // RNE to bf16
    return (short)(u >> 16);
}

// ---- Kernel 1: centers f32 [N][K] -> cbF in MFMA-fragment order + chalf ----
// cbF layout: [kstep][ntile][lane][16B]; lane = (n&15) + ((k>>3)&3)*16,
// frag bytes = k&7 (8 consecutive k per lane). Slab per kstep = (N/16)*1024 B.
__global__ __launch_bounds__(128) void cast_centers_frag(const float* __restrict__ c,
                                                         short* __restrict__ cbF,
                                                         float* __restrict__ chalf, int K) {
    const int n = blockIdx.x;
    const int i = threadIdx.x;
    const int k0 = i * 8;
    const float* row = c + (size_t)n * K;
    float4 a = *(const float4*)(row + k0);
    float4 b = *(const float4*)(row + k0 + 4);
    float s = a.x * a.x + a.y * a.y + a.z * a.z + a.w * a.w +
              b.x * b.x + b.y * b.y + b.z * b.z + b.w * b.w;
    short8 o;
    o[0] = f2bf(a.x); o[1] = f2bf(a.y); o[2] = f2bf(a.z); o[3] = f2bf(a.w);
    o[4] = f2bf(b.x); o[5] = f2bf(b.y); o[6] = f2bf(b.z); o[7] = f2bf(b.w);
    const size_t slab = (size_t)(K / 16) * 1024;
    const size_t addr = (size_t)(k0 >> 5) * slab + (size_t)(n >> 4) * 1024 +
                        (size_t)((n & 15) + ((k0 >> 3) & 3) * 16) * 16;
    *(short8*)((char*)cbF + addr) = o;
#pragma unroll
    for (int off = 32; off; off >>= 1) s += __shfl_xor(s, off);
    __shared__ float red[2];
    if ((i & 63) == 0) red[i >> 6] = s;
    __syncthreads();
    if (i == 0) chalf[n] = 0.5f * (red[0] + red[1]);
}

// ------------- Kernel 2: fused GEMM (64 x FULL-ROW 1024) + log-softmax epilogue -------------
// logits[b,k] = x_b . c_k - 0.5*||c_k||^2  (row-constant -0.5*||x||^2 cancels in log_softmax)
// out[b,k] = logits[b,k] - logsumexp_k(logits[b,:])
//
// R15 = R13 + NON-TEMPORAL streaming: every B/x byte is touched exactly once per CU
// (zero L1 reuse by construction), so B fragment loads and x loads use
// __builtin_nontemporal_load (global_load nt: no L1 allocation; L2 reuse across blocks
// unaffected) and the final output uses nontemporal stores. Hypothesis: the ~3400
// cyc/kstep K-loop is bound by the L1 line-allocation path for streaming misses
// (~19-26 B/cyc/CU, m13-class), not by barriers/occupancy/L2 (falsified R9-R14).
// 16 waves, wave tile 64x64, A ring-4 fragment slabs folded into the loop.
#define SCR 16384

__global__ __launch_bounds__(1024, 1) void fused_kernel(
    const float* __restrict__ x,     // [M][K] f32
    const short* __restrict__ cbF,   // fragment-order centers
    const float* __restrict__ chalf, // [N]
    float* __restrict__ out,         // [M][N]
    int M, int N, int K) {
    __shared__ char lds[16384 + 4608];
    const int t = threadIdx.x;
    const int l = t & 63, w = t >> 6, lr = l & 15, hi = l >> 4;
    const int brow = blockIdx.x * 64;

    // B: wave w covers n-tiles w*4..w*4+3
    const char* bbase = (const char*)cbF + w * 4096 + l * 16;

    // A-staging: thread t -> row ar = t>>4, k-pair kp = t&15 (k = 2*kp)
    const int ar = t >> 4, kp = t & 15;
    const float* xsrc = x + (size_t)(brow + ar) * K + kp * 2;
    const int awofs = (ar >> 4) * 1024 + ((ar & 15) + (kp >> 2) * 16) * 16 + (kp & 3) * 4;

#define LDB(dst, ks) do { _Pragma("unroll")                                      \
    for (int j = 0; j < 4; ++j)                                                  \
        dst[j] = __builtin_nontemporal_load(                                     \
            (const short8*)(bbase + (size_t)(ks) * 65536 + j * 1024)); } while (0)

#define LDX(ofs) __builtin_nontemporal_load((const f32x2*)(xsrc + (ofs)))

#define AW(slot, fv) do {                                                        \
    unsigned p_ = ((unsigned)(unsigned short)f2bf((fv).y) << 16) |               \
                  (unsigned)(unsigned short)f2bf((fv).x);                        \
    *(unsigned*)(lds + ((slot) & 3) * 4096 + awofs) = p_; } while (0)

    f32x4 acc[4][4];
#pragma unroll
    for (int m = 0; m < 4; ++m)
#pragma unroll
        for (int n = 0; n < 4; ++n)
#pragma unroll
            for (int q = 0; q < 4; ++q) acc[m][n][q] = 0.f;

    short8 Ba[4], Bb[4];
    f32x2 xf0, xf1;

    // ---- prologue: prime slots 0,1; x(2),x(3) + B(0),B(1) in flight ----
    xf0 = LDX(0);
    xf1 = LDX(32);
    LDB(Ba, 0);
    AW(0, xf0);
    AW(1, xf1);
    xf0 = LDX(64);
    xf1 = LDX(96);
    LDB(Bb, 1);
    asm volatile("s_waitcnt lgkmcnt(0)" ::: "memory");
    __builtin_amdgcn_s_barrier();

#define MFMACL(Bcur) do {                                                        \
    __builtin_amdgcn_s_setprio(1);                                               \
    _Pragma("unroll")                                                            \
    for (int m = 0; m < 4; ++m)                                                  \
        _Pragma("unroll")                                                        \
        for (int n = 0; n < 4; ++n)                                              \
            acc[m][n] = __builtin_amdgcn_mfma_f32_16x16x32_bf16(af[m], Bcur[n],  \
                                                                acc[m][n], 0, 0, 0); \
    __builtin_amdgcn_s_setprio(0); } while (0)

#define AREAD(slot) short8 af[4];                                                \
    _Pragma("unroll")                                                            \
    for (int m = 0; m < 4; ++m)                                                  \
        af[m] = *(const short8*)(lds + ((slot) & 3) * 4096 + m * 1024 + l * 16);

#define SYNCP() do {                                                             \
    asm volatile("s_waitcnt lgkmcnt(0)" ::: "memory");                           \
    __builtin_amdgcn_s_barrier();                                                \
    __builtin_amdgcn_sched_barrier(0); } while (0)

    // ---- main loop: full body for ks <= 27 (x-issue needs ks+4 <= 31) ----
    for (int ks = 0; ks < 28; ks += 2) {
        {
            AREAD(ks); SYNCP();
            MFMACL(Ba);
            AW(ks + 2, xf0);
            LDB(Ba, ks + 2);
            xf0 = LDX((size_t)(ks + 4) * 32);
        }
        {
            AREAD(ks + 1); SYNCP();
            MFMACL(Bb);
            AW(ks + 3, xf1);
            LDB(Bb, ks + 3);
            xf1 = LDX((size_t)(ks + 5) * 32);
        }
    }
    // ---- peeled tail: ks = 28..31 ----
    { AREAD(28); SYNCP(); MFMACL(Ba); AW(30, xf0); LDB(Ba, 30); }
    { AREAD(29); SYNCP(); MFMACL(Bb); AW(31, xf1); LDB(Bb, 31); }
    { AREAD(30); SYNCP(); MFMACL(Ba); }
    { AREAD(31); SYNCP(); MFMACL(Bb); }
#undef AREAD
#undef MFMACL
#undef SYNCP
#undef LDB
#undef LDX
#undef AW

    // ================= fused log-softmax epilogue =================
    // C/D frag layout: col = lane&15, row = (lane>>4)*4 + q.
    // Lane holds rows R = m*16 + hi*4 + q, cols w*64 + n*16 + lr.
    float ch[4];
#pragma unroll
    for (int n = 0; n < 4; ++n) ch[n] = chalf[w * 64 + n * 16 + lr];

    // pass 1: per-lane max over n, reduce over lr-lanes, cross-wave via LDS scratch
    float pm[4][4];
#pragma unroll
    for (int m = 0; m < 4; ++m)
#pragma unroll
        for (int q = 0; q < 4; ++q) {
            float v = acc[m][0][q] - ch[0];
#pragma unroll
            for (int n = 1; n < 4; ++n) v = fmaxf(v, acc[m][n][q] - ch[n]);
            pm[m][q] = v;
        }
#pragma unroll
    for (int d = 1; d <= 8; d <<= 1)
#pragma unroll
        for (int m = 0; m < 4; ++m)
#pragma unroll
            for (int q = 0; q < 4; ++q) pm[m][q] = fmaxf(pm[m][q], __shfl_xor(pm[m][q], d));
    if (lr == 0) {
#pragma unroll
        for (int m = 0; m < 4; ++m)
#pragma unroll
            for (int q = 0; q < 4; ++q)
                *(float*)(lds + SCR + (m * 16 + hi * 4 + q) * 64 + w * 4) = pm[m][q]; // wmax[R][w16]
    }
    __syncthreads();
    if (t < 64) {
        float g = -1e30f;
#pragma unroll
        for (int j = 0; j < 4; ++j) {
            float4 a = *(const float4*)(lds + SCR + t * 64 + j * 16);
            g = fmaxf(g, fmaxf(fmaxf(a.x, a.y), fmaxf(a.z, a.w)));
        }
        *(float*)(lds + SCR + 4096 + t * 4) = g;                                      // gmax[R]
    }
    __syncthreads();

    // pass 2: sum of exp
    float ps[4][4];
#pragma unroll
    for (int m = 0; m < 4; ++m)
#pragma unroll
        for (int q = 0; q < 4; ++q) {
            const float g = *(const float*)(lds + SCR + 4096 + (m * 16 + hi * 4 + q) * 4);
            float s = 0.f;
#pragma unroll
            for (int n = 0; n < 4; ++n) s += __expf(acc[m][n][q] - ch[n] - g);
            ps[m][q] = s;
        }
#pragma unroll
    for (int d = 1; d <= 8; d <<= 1)
#pragma unroll
        for (int m = 0; m < 4; ++m)
#pragma unroll
            for (int q = 0; q < 4; ++q) ps[m][q] += __shfl_xor(ps[m][q], d);
    if (lr == 0) {
#pragma unroll
        for (int m = 0; m < 4; ++m)
#pragma unroll
            for (int q = 0; q < 4; ++q)
                *(float*)(lds + SCR + (m * 16 + hi * 4 + q) * 64 + w * 4) = ps[m][q];  // wsum[R][w16]
    }
    __syncthreads();
    if (t < 64) {
        float s = 0.f;
#pragma unroll
        for (int j = 0; j < 4; ++j) {
            float4 a = *(const float4*)(lds + SCR + t * 64 + j * 16);
            s += a.x + a.y + a.z + a.w;
        }
        *(float*)(lds + SCR + 4352 + t * 4) =
            *(const float*)(lds + SCR + 4096 + t * 4) + __logf(s);                    // lse[R]
    }
    __syncthreads();

    // write final output (nontemporal: never re-read)
#pragma unroll
    for (int m = 0; m < 4; ++m)
#pragma unroll
        for (int q = 0; q < 4; ++q) {
            const int R = m * 16 + hi * 4 + q;
            const float lse = *(const float*)(lds + SCR + 4352 + R * 4);
            float* orow = out + (size_t)(brow + R) * N + w * 64 + lr;
#pragma unroll
            for (int n = 0; n < 4; ++n)
                __builtin_nontemporal_store(acc[m][n][q] - ch[n] - lse, &orow[n * 16]);
        }
}

extern "C" void kernel_launch(void* const* d_in, const int* in_sizes, int n_in,
                              void* d_out, int out_size, void* d_ws, size_t ws_size,
                              hipStream_t stream) {
    const float* x = (const float*)d_in[0];
    const float* c = (const float*)d_in[1];
    float* out = (float*)d_out;

    int dim = (int)(sqrt((double)in_sizes[1]) + 0.5);   // 1024
    int batch = in_sizes[0] / dim;                      // 16384

    // workspace layout: [cbF bf16 fragment-order][chalf f32]
    size_t cb_bytes = (size_t)dim * dim * 2;
    short* cbF = (short*)d_ws;
    float* chalf = (float*)((char*)d_ws + cb_bytes);

    cast_centers_frag<<<dim, 128, 0, stream>>>(c, cbF, chalf, dim);

    fused_kernel<<<batch / 64, 1024, 0, stream>>>(x, cbF, chalf, out, batch, dim, dim);
}

// Round 18
// 55.014 us; speedup vs baseline: 1.4082x; 1.4082x over previous
//
#include <hip/hip_runtime.h>
#include <math.h>

typedef __attribute__((ext_vector_type(8))) short short8;
typedef __attribute__((ext_vector_type(4))) float f32x4;
typedef __attribute__((ext_vector_type(4))) unsigned int u32x4;

__device__ inline short f2bf(float f) {
    unsigned u = __float_as_uint(f);
    u += 0x7FFFu + ((u >> 16) & 1u);   // RNE to bf16
    return (short)(u >> 16);
}

// ---- Kernel 1: centers f32 [N][K] -> cbF in MFMA-fragment order + chalf ----
// cbF layout: [kstep][ntile][lane][16B]; lane = (n&15) + ((k>>3)&3)*16,
// frag bytes = k&7 (8 consecutive k per lane). Slab per kstep = (N/16)*1024 B.
__global__ __launch_bounds__(128) void cast_centers_frag(const float* __restrict__ c,
                                                         short* __restrict__ cbF,
                                                         float* __restrict__ chalf, int K) {
    const int n = blockIdx.x;
    const int i = threadIdx.x;
    const int k0 = i * 8;
    const float* row = c + (size_t)n * K;
    float4 a = *(const float4*)(row + k0);
    float4 b = *(const float4*)(row + k0 + 4);
    float s = a.x * a.x + a.y * a.y + a.z * a.z + a.w * a.w +
              b.x * b.x + b.y * b.y + b.z * b.z + b.w * b.w;
    short8 o;
    o[0] = f2bf(a.x); o[1] = f2bf(a.y); o[2] = f2bf(a.z); o[3] = f2bf(a.w);
    o[4] = f2bf(b.x); o[5] = f2bf(b.y); o[6] = f2bf(b.z); o[7] = f2bf(b.w);
    const size_t slab = (size_t)(K / 16) * 1024;
    const size_t addr = (size_t)(k0 >> 5) * slab + (size_t)(n >> 4) * 1024 +
                        (size_t)((n & 15) + ((k0 >> 3) & 3) * 16) * 16;
    *(short8*)((char*)cbF + addr) = o;
#pragma unroll
    for (int off = 32; off; off >>= 1) s += __shfl_xor(s, off);
    __shared__ float red[2];
    if ((i & 63) == 0) red[i >> 6] = s;
    __syncthreads();
    if (i == 0) chalf[n] = 0.5f * (red[0] + red[1]);
}

// ------------- Kernel 2: fused GEMM (64 x FULL-ROW 1024) + log-softmax epilogue -------------
// logits[b,k] = x_b . c_k - 0.5*||c_k||^2  (row-constant -0.5*||x||^2 cancels in log_softmax)
// out[b,k] = logits[b,k] - logsumexp_k(logits[b,:])
//
// R18 = R16/R17 intent, compile-fixed: typeless __builtin_amdgcn_raw_buffer_load_b128
// (this ROCm's available builtin) with aux=1 (sc0: L1 bypass, L2 served) for the B
// fragment streams. Exact R11 structure otherwise (best: 55.4 us). Rationale: B streams
// 64 KB/kstep through a 32-KB L1 with zero reuse (thrash); sc0 skips L1 allocation
// without R15-nt's L2-eviction side effect.
#define SCR 16384

__global__ __launch_bounds__(512, 2) void fused_kernel(
    const float* __restrict__ x,     // [M][K] f32
    const short* __restrict__ cbF,   // fragment-order centers
    const float* __restrict__ chalf, // [N]
    float* __restrict__ out,         // [M][N]
    int M, int N, int K) {
    __shared__ char lds[16384 + 4608];
    const int t = threadIdx.x;
    const int l = t & 63, w = t >> 6, lr = l & 15, hi = l >> 4;
    const int brow = blockIdx.x * 64;

    // Buffer resource for cbF (2 MiB, stride 0, raw dword access).
    __amdgpu_buffer_rsrc_t rsv = __builtin_amdgcn_make_buffer_rsrc(
        (void*)cbF, (short)0, 0x00200000u, 0x00020000u);
    const int bvo = w * 8192 + l * 16;   // wave's ntile block + lane offset

    // A-staging addressing: thread t -> row ar = t>>3, k-local c8*4..c8*4+3
    const int ar = t >> 3, c8 = t & 7;
    const float* xsrc = x + (size_t)(brow + ar) * K + c8 * 4;
    const int awofs = (ar >> 4) * 1024 + (ar & 15) * 16 + (c8 >> 1) * 256 + (c8 & 1) * 8;

#define LDB(dst, ks) do { _Pragma("unroll")                                      \
    for (int j = 0; j < 8; ++j) {                                                \
        u32x4 tmp_ = __builtin_amdgcn_raw_buffer_load_b128(                      \
            rsv, bvo + (ks) * 65536 + j * 1024, 0, 1 /*sc0: L1 bypass*/);        \
        dst[j] = __builtin_bit_cast(short8, tmp_);                               \
    } } while (0)

#define AW(slot, fv) do {                                                        \
    short4 p_;                                                                   \
    p_.x = f2bf((fv).x); p_.y = f2bf((fv).y);                                    \
    p_.z = f2bf((fv).z); p_.w = f2bf((fv).w);                                    \
    *(short4*)(lds + ((slot) & 3) * 4096 + awofs) = p_; } while (0)

    f32x4 acc[4][8];
#pragma unroll
    for (int m = 0; m < 4; ++m)
#pragma unroll
        for (int n = 0; n < 8; ++n)
#pragma unroll
            for (int q = 0; q < 4; ++q) acc[m][n][q] = 0.f;

    short8 Ba[8], Bb[8];
    float4 xf0, xf1;

    // ---- prologue: prime slots 0,1; x(2),x(3) + B(0),B(1) in flight ----
    xf0 = *(const float4*)(xsrc);
    xf1 = *(const float4*)(xsrc + 32);
    LDB(Ba, 0);
    AW(0, xf0);
    AW(1, xf1);
    xf0 = *(const float4*)(xsrc + 64);
    xf1 = *(const float4*)(xsrc + 96);
    LDB(Bb, 1);
    asm volatile("s_waitcnt lgkmcnt(0)" ::: "memory");
    __builtin_amdgcn_s_barrier();

#define MFMACL(Bcur) do {                                                        \
    __builtin_amdgcn_s_setprio(1);                                               \
    _Pragma("unroll")                                                            \
    for (int m = 0; m < 4; ++m)                                                  \
        _Pragma("unroll")                                                        \
        for (int n = 0; n < 8; ++n)                                              \
            acc[m][n] = __builtin_amdgcn_mfma_f32_16x16x32_bf16(af[m], Bcur[n],  \
                                                                acc[m][n], 0, 0, 0); \
    __builtin_amdgcn_s_setprio(0); } while (0)

#define AREAD(slot) short8 af[4];                                                \
    _Pragma("unroll")                                                            \
    for (int m = 0; m < 4; ++m)                                                  \
        af[m] = *(const short8*)(lds + ((slot) & 3) * 4096 + m * 1024 + l * 16);

#define SYNCP() do {                                                             \
    asm volatile("s_waitcnt lgkmcnt(0)" ::: "memory");                           \
    __builtin_amdgcn_s_barrier();                                                \
    __builtin_amdgcn_sched_barrier(0); } while (0)

    // ---- main loop: full body for ks <= 27 (x-issue needs ks+4 <= 31) ----
    for (int ks = 0; ks < 28; ks += 2) {
        {
            AREAD(ks); SYNCP();
            MFMACL(Ba);
            AW(ks + 2, xf0);
            LDB(Ba, ks + 2);
            xf0 = *(const float4*)(xsrc + (size_t)(ks + 4) * 32);
        }
        {
            AREAD(ks + 1); SYNCP();
            MFMACL(Bb);
            AW(ks + 3, xf1);
            LDB(Bb, ks + 3);
            xf1 = *(const float4*)(xsrc + (size_t)(ks + 5) * 32);
        }
    }
    // ---- peeled tail: ks = 28..31 ----
    { AREAD(28); SYNCP(); MFMACL(Ba); AW(30, xf0); LDB(Ba, 30); }
    { AREAD(29); SYNCP(); MFMACL(Bb); AW(31, xf1); LDB(Bb, 31); }
    { AREAD(30); SYNCP(); MFMACL(Ba); }
    { AREAD(31); SYNCP(); MFMACL(Bb); }
#undef AREAD
#undef MFMACL
#undef SYNCP
#undef LDB
#undef AW

    // ================= fused log-softmax epilogue =================
    // C/D frag layout: col = lane&15, row = (lane>>4)*4 + q.
    // Lane holds rows R = m*16 + hi*4 + q, cols w*128 + n*16 + lr.
    float ch[8];
#pragma unroll
    for (int n = 0; n < 8; ++n) ch[n] = chalf[w * 128 + n * 16 + lr];

    // pass 1: per-lane max over n, reduce over lr-lanes, cross-wave via LDS scratch
    float pm[4][4];
#pragma unroll
    for (int m = 0; m < 4; ++m)
#pragma unroll
        for (int q = 0; q < 4; ++q) {
            float v = acc[m][0][q] - ch[0];
#pragma unroll
            for (int n = 1; n < 8; ++n) v = fmaxf(v, acc[m][n][q] - ch[n]);
            pm[m][q] = v;
        }
#pragma unroll
    for (int d = 1; d <= 8; d <<= 1)
#pragma unroll
        for (int m = 0; m < 4; ++m)
#pragma unroll
            for (int q = 0; q < 4; ++q) pm[m][q] = fmaxf(pm[m][q], __shfl_xor(pm[m][q], d));
    if (lr == 0) {
#pragma unroll
        for (int m = 0; m < 4; ++m)
#pragma unroll
            for (int q = 0; q < 4; ++q)
                *(float*)(lds + SCR + (m * 16 + hi * 4 + q) * 32 + w * 4) = pm[m][q]; // wmax[R][w]
    }
    __syncthreads();
    if (t < 64) {
        float4 a = *(const float4*)(lds + SCR + t * 32);
        float4 b = *(const float4*)(lds + SCR + t * 32 + 16);
        float g = fmaxf(fmaxf(fmaxf(a.x, a.y), fmaxf(a.z, a.w)),
                        fmaxf(fmaxf(b.x, b.y), fmaxf(b.z, b.w)));
        *(float*)(lds + SCR + 4096 + t * 4) = g;                                      // gmax[R]
    }
    __syncthreads();

    // pass 2: sum of exp
    float ps[4][4];
#pragma unroll
    for (int m = 0; m < 4; ++m)
#pragma unroll
        for (int q = 0; q < 4; ++q) {
            const float g = *(const float*)(lds + SCR + 4096 + (m * 16 + hi * 4 + q) * 4);
            float s = 0.f;
#pragma unroll
            for (int n = 0; n < 8; ++n) s += __expf(acc[m][n][q] - ch[n] - g);
            ps[m][q] = s;
        }
#pragma unroll
    for (int d = 1; d <= 8; d <<= 1)
#pragma unroll
        for (int m = 0; m < 4; ++m)
#pragma unroll
            for (int q = 0; q < 4; ++q) ps[m][q] += __shfl_xor(ps[m][q], d);
    if (lr == 0) {
#pragma unroll
        for (int m = 0; m < 4; ++m)
#pragma unroll
            for (int q = 0; q < 4; ++q)
                *(float*)(lds + SCR + 2048 + (m * 16 + hi * 4 + q) * 32 + w * 4) = ps[m][q]; // wsum[R][w]
    }
    __syncthreads();
    if (t < 64) {
        float4 a = *(const float4*)(lds + SCR + 2048 + t * 32);
        float4 b = *(const float4*)(lds + SCR + 2048 + t * 32 + 16);
        float s = (a.x + a.y + a.z + a.w) + (b.x + b.y + b.z + b.w);
        *(float*)(lds + SCR + 4352 + t * 4) =
            *(const float*)(lds + SCR + 4096 + t * 4) + __logf(s);                    // lse[R]
    }
    __syncthreads();

    // write final output
#pragma unroll
    for (int m = 0; m < 4; ++m)
#pragma unroll
        for (int q = 0; q < 4; ++q) {
            const int R = m * 16 + hi * 4 + q;
            const float lse = *(const float*)(lds + SCR + 4352 + R * 4);
            float* orow = out + (size_t)(brow + R) * N + w * 128 + lr;
#pragma unroll
            for (int n = 0; n < 8; ++n)
                orow[n * 16] = acc[m][n][q] - ch[n] - lse;
        }
}

extern "C" void kernel_launch(void* const* d_in, const int* in_sizes, int n_in,
                              void* d_out, int out_size, void* d_ws, size_t ws_size,
                              hipStream_t stream) {
    const float* x = (const float*)d_in[0];
    const float* c = (const float*)d_in[1];
    float* out = (float*)d_out;

    int dim = (int)(sqrt((double)in_sizes[1]) + 0.5);   // 1024
    int batch = in_sizes[0] / dim;                      // 16384

    // workspace layout: [cbF bf16 fragment-order][chalf f32]
    size_t cb_bytes = (size_t)dim * dim * 2;
    short* cbF = (short*)d_ws;
    float* chalf = (float*)((char*)d_ws + cb_bytes);

    cast_centers_frag<<<dim, 128, 0, stream>>>(c, cbF, chalf, dim);

    fused_kernel<<<batch / 64, 512, 0, stream>>>(x, cbF, chalf, out, batch, dim, dim);
}